// Round 3
// baseline (168.354 us; speedup 1.0000x reference)
//
#include <hip/hip_runtime.h>

// Multi-scale gradient-difference loss as line-parallel reductions.
// R9: back to R0's full-residency structure (2046 static blocks = 8184 waves
// ~= the chip's 8192 wave slots; R8 proved halving residency costs ~2x on
// these latency-bound passes). One targeted change: pass1 persists its staged
// line buffers to linear scratch (coalesced float4 stores); pass2 reloads
// with 2 coalesced loads/thread instead of re-doing the 7-array uncoalesced
// V/diagonal gathers. The gather is paid ONCE. Same grid dims in both passes
// -> same block->XCD placement -> pass2 scratch reads are same-XCD L2-hot.
// final_kernel folded into pass2 via last-block-done (R8-validated).

#define NSCALES 67
#define IMG_H 256
#define IMG_W 256
#define NPIX 65536
#define NLINES 2046          // 512 rows (H) + 512 cols (V) + 1022 diagonals (D)
#define LMAX_PAD 320         // 256 positions + 64 zero pad (max tap index 318)

// ws layout:
//  doubles [0..3] b0 {S1,S2,posCnt,sumAbsPrd}  [4..7] b1 same
//  [8..9] roiSum[b]   [18] done ctr (int)   [24..25] T1[b]
//  byte offset 4096+: scratch, 512 float4 per line (bufA[256], bufB[256])

__device__ __forceinline__ double wave_red(double v) {
#pragma unroll
  for (int o = 32; o > 0; o >>= 1) v += __shfl_down(v, o, 64);
  return v;
}

__device__ __forceinline__ void decode_line(int id, int& b, int& base, int& stride, int& L) {
  if (id < 512) {                      // horizontal row
    b = id >> 8; int y = id & 255;
    base = y * IMG_W; stride = 1; L = IMG_W;
  } else if (id < 1024) {              // vertical column
    int t = id - 512; b = t >> 8;
    base = t & 255; stride = IMG_W; L = IMG_H;
  } else {                             // diagonal c = x - y in [-255,255]
    int t = id - 1024; b = (t >= 511) ? 1 : 0;
    int d = t - b * 511; int c = d - 255;
    int ac = (c < 0) ? -c : c;
    base = (c < 0) ? (-c) * IMG_W : c;
    stride = IMG_W + 1; L = 256 - ac;
  }
}

// #scales valid for quarter q (centers [64q, 64q+63]): s = 1+3k <= min(L-1-64q, 199)
__device__ __forceinline__ int scale_count(int L, int q) {
  int rem = L - 1 - (q << 6);
  int kcnt = (rem >= 1) ? ((rem - 1) / 3 + 1) : 0;
  return (kcnt > NSCALES) ? NSCALES : kcnt;
}

// Stage line; returns this tid's ROI value (position tid) for the ROI sum.
__device__ __forceinline__ float stage_line(
    const float* __restrict__ Pred, const float* __restrict__ GT,
    const float* __restrict__ ROI, int b, int base, int stride, int L,
    int tid, float4* bufA, float4* bufB) {
  const float* P = Pred + b * (3 * NPIX);
  const float* G = GT + b * (3 * NPIX);
  const float* R = ROI + b * NPIX;
  float r = 0.f, p0 = 0.f, p1 = 0.f, p2 = 0.f, g0 = 0.f, g1 = 0.f, g2 = 0.f;
  if (tid < L) {
    int a = base + tid * stride;
    r = R[a];
    p0 = P[a]; p1 = P[a + NPIX]; p2 = P[a + 2 * NPIX];
    g0 = G[a]; g1 = G[a + NPIX]; g2 = G[a + 2 * NPIX];
  }
  bufA[tid] = make_float4(r, p0, p1, p2);
  bufB[tid] = make_float4(g0, g1, g2, 0.f);
  if (tid < LMAX_PAD - 256) {
    bufA[256 + tid] = make_float4(0.f, 0.f, 0.f, 0.f);
    bufB[256 + tid] = make_float4(0.f, 0.f, 0.f, 0.f);
  }
  __syncthreads();
  return r;
}

__device__ __forceinline__ double aread(const double* p) {
  return __hip_atomic_load(p, __ATOMIC_RELAXED, __HIP_MEMORY_SCOPE_AGENT);
}

extern "C" __global__ void __launch_bounds__(256, 8) pass1_kernel(
    const float* __restrict__ Pred, const float* __restrict__ GT,
    const float* __restrict__ ROI, double* __restrict__ ws) {
  __shared__ float4 bufA[LMAX_PAD];    // {r, p0, p1, p2}
  __shared__ float4 bufB[LMAX_PAD];    // {g0, g1, g2, 0}
  __shared__ double red[4][5];
  const int id = blockIdx.x;
  const int tid = threadIdx.x;
  const int wid = tid >> 6, lane = tid & 63;

  int b, base, stride, L;
  decode_line(id, b, base, stride, L);
  float stg_r = stage_line(Pred, GT, ROI, b, base, stride, L, tid, bufA, bufB);

  // persist staged line for pass2 (coalesced; fire-and-forget during compute)
  float4* S4 = (float4*)((char*)ws + 4096);
  S4[(size_t)id * 512 + tid] = bufA[tid];
  S4[(size_t)id * 512 + 256 + tid] = bufB[tid];

  float f1 = 0.f, f2 = 0.f, fp = 0.f;
  int pci = 0;
  int P = 0;                            // task prefix
  for (int q = 0; q < 4; ++q) {
    const int Kq = scale_count(L, q);
    int k = (wid - P) & 3;              // round-robin task deal across 4 waves
    if (k < Kq) {
      const int c = (q << 6) + lane;
      const float4 cA = bufA[c];
      const float4 cB = bufB[c];
      const float cr = cA.x, cp0 = cA.y, cp1 = cA.z, cp2 = cA.w;
      const float cg0 = cB.x, cg1 = cB.y, cg2 = cB.z;
      const float4* tA = &bufA[c + 1 + 3 * k];
      const float4* tB = &bufB[c + 1 + 3 * k];
#pragma unroll 2
      for (; k < Kq; k += 4) {
        float4 t0 = tA[0];
        float4 t1 = tB[0];
        tA += 12; tB += 12;             // s += 12
        float rr = cr * t0.x;
#define L1BODY(cp, cg, tp, tg)                                   \
        {                                                        \
          float dP = rr * (cp - tp);                             \
          float dG = rr * (cg - tg);                             \
          float qq = dP * __builtin_amdgcn_rcpf(dG + 1e-5f);     \
          float aG = fabsf(dG);                                  \
          f1 += fmaxf(aG * qq, 0.f);                             \
          if (qq > 0.f) f2 += aG;                                \
          if (dG > 0.f) pci++;                                   \
          fp += fabsf(dP);                                       \
        }
        L1BODY(cp0, cg0, t0.y, t1.x)
        L1BODY(cp1, cg1, t0.z, t1.y)
        L1BODY(cp2, cg2, t0.w, t1.z)
#undef L1BODY
      }
    }
    P += Kq;
  }

  double w0 = wave_red((double)f1);
  double w1 = wave_red((double)f2);
  double w2 = wave_red((double)pci);
  double w3 = wave_red((double)fp);
  double w4 = wave_red((double)stg_r);  // ROI partial: position tid, once/block
  if (lane == 0) {
    red[wid][0] = w0; red[wid][1] = w1; red[wid][2] = w2;
    red[wid][3] = w3; red[wid][4] = w4;
  }
  __syncthreads();
  if (tid < 4)
    unsafeAtomicAdd(&ws[b * 4 + tid],
                    red[0][tid] + red[1][tid] + red[2][tid] + red[3][tid]);
  if (tid == 4 && id < 512)             // H rows tile the image exactly once
    unsafeAtomicAdd(&ws[8 + b], red[0][4] + red[1][4] + red[2][4] + red[3][4]);
}

extern "C" __global__ void __launch_bounds__(256, 8) pass2_kernel(
    double* __restrict__ ws, float* __restrict__ out) {
  __shared__ float4 bufA[LMAX_PAD];
  __shared__ float4 bufB[LMAX_PAD];
  __shared__ double red[4];
  __shared__ float s_invC[2];
  const int id = blockIdx.x;
  const int tid = threadIdx.x;
  const int wid = tid >> 6, lane = tid & 63;
  int* done = (int*)&ws[18];

  int b, base, stride, L;
  decode_line(id, b, base, stride, L);

  if (tid < 2) {                        // invC per batch; pass1 sums are
    double S1 = ws[tid * 4 + 0];        // coherent across the kernel boundary
    double S2 = ws[tid * 4 + 1];
    float cc = (float)(S1 / (S2 + 1e-4));
    s_invC[tid] = (cc > 1e-4f) ? (float)(1.0 / (double)cc) : 1.0f;
  }

  // restage from linear scratch: 2 coalesced float4 loads (vs 7 gathers)
  const float4* S4 = (const float4*)((const char*)ws + 4096);
  bufA[tid] = S4[(size_t)id * 512 + tid];
  bufB[tid] = S4[(size_t)id * 512 + 256 + tid];
  if (tid < LMAX_PAD - 256) {
    bufA[256 + tid] = make_float4(0.f, 0.f, 0.f, 0.f);
    bufB[256 + tid] = make_float4(0.f, 0.f, 0.f, 0.f);
  }
  __syncthreads();

  const float invC = s_invC[b];
  float f = 0.f;
  int P = 0;
  for (int q = 0; q < 4; ++q) {
    const int Kq = scale_count(L, q);
    int k = (wid - P) & 3;
    if (k < Kq) {
      const int c = (q << 6) + lane;
      const float4 cA = bufA[c];
      const float4 cB = bufB[c];
      const float cr = cA.x, cp0 = cA.y, cp1 = cA.z, cp2 = cA.w;
      const float cg0 = cB.x, cg1 = cB.y, cg2 = cB.z;
      const float4* tA = &bufA[c + 1 + 3 * k];
      const float4* tB = &bufB[c + 1 + 3 * k];
#pragma unroll 2
      for (; k < Kq; k += 4) {
        float4 t0 = tA[0];
        float4 t1 = tB[0];
        tA += 12; tB += 12;
        float rr = cr * t0.x;
        // |difGT - difPrd/c| = rr * |(g-gt) - (p-pt)*invC|   (rr in {0,1})
        f += rr * fabsf((cg0 - t1.x) - (cp0 - t0.y) * invC);
        f += rr * fabsf((cg1 - t1.y) - (cp1 - t0.z) * invC);
        f += rr * fabsf((cg2 - t1.z) - (cp2 - t0.w) * invC);
      }
    }
    P += Kq;
  }
  double t = wave_red((double)f);
  if (lane == 0) red[wid] = t;
  __syncthreads();
  if (tid == 0) {
    unsafeAtomicAdd(&ws[24 + b], red[0] + red[1] + red[2] + red[3]);
    __threadfence();                    // release T1 before arriving
    int rank = __hip_atomic_fetch_add(done, 1, __ATOMIC_ACQ_REL,
                                      __HIP_MEMORY_SCOPE_AGENT);
    if (rank == NLINES - 1) {           // last block computes the final loss
      double loss = 0.0;
      for (int bb = 0; bb < 2; ++bb) {
        double S1 = aread(&ws[bb * 4 + 0]), S2 = aread(&ws[bb * 4 + 1]);
        double PC = aread(&ws[bb * 4 + 2]), SP = aread(&ws[bb * 4 + 3]);
        double RS = aread(&ws[8 + bb]);
        float cc = (float)(S1 / (S2 + 1e-4));
        out[1 + bb] = cc;               // NormConst
        double term1 = (cc > 1e-4f) ? aread(&ws[24 + bb]) / (603.0 * 65536.0) : 0.0;
        float meanPrd = (float)(SP / PC);
        bool big = RS > 200.0;
        float t2 = (big && meanPrd > 30.f && cc > 10.f) ? (meanPrd - 30.f) : 0.f;
        float fact = 0.1f / (cc + 0.001f);
        float t3 = (big && meanPrd < 2.f && cc < 0.1f) ? (0.2f - meanPrd) * fact : 0.f;
        loss += term1 + (double)(t2 + t3);
      }
      out[0] = (float)loss;
    }
  }
}

extern "C" void kernel_launch(void* const* d_in, const int* in_sizes, int n_in,
                              void* d_out, int out_size, void* d_ws, size_t ws_size,
                              hipStream_t stream) {
  (void)in_sizes; (void)n_in; (void)out_size; (void)ws_size;
  const float* Pred = (const float*)d_in[0];
  const float* GT = (const float*)d_in[1];
  const float* ROI = (const float*)d_in[2];
  float* out = (float*)d_out;
  double* ws = (double*)d_ws;

  hipMemsetAsync(d_ws, 0, 32 * sizeof(double), stream);   // accums + done ctr
  hipLaunchKernelGGL(pass1_kernel, dim3(NLINES), dim3(256), 0, stream,
                     Pred, GT, ROI, ws);
  hipLaunchKernelGGL(pass2_kernel, dim3(NLINES), dim3(256), 0, stream,
                     ws, out);
}

// Round 4
// 106.497 us; speedup vs baseline: 1.5808x; 1.5808x over previous
//
#include <hip/hip_runtime.h>

// Multi-scale gradient-difference loss as line-parallel reductions.
// R10: exact R0 structure (4 dispatches; verified 128us) + striped atomics.
// Post-mortems: R7 grid-barrier (283us: acquire-spin = per-iter cache inv),
// R8/R9 last-block-done (~+35us: per-block threadfence+acq_rel = per-block
// L2 writeback/invalidate), R9 scratch persist (no help: pass2's stage was
// already L2-hot; its stall was elsewhere). This round: all pass1 sums
// previously hit ONE 64B line (ws[0..7]) with ~8700 serialized f64 atomic
// RMWs (~4ns each ~= 35us, bursting in the tail when the 1024 equal-work
// H/V blocks finish together). Now striped 8x by blockIdx&7 with one cache
// line per (component, batch, stripe): 64 hot lines, ~256 ops/line, L2-bank
// parallel. Final kernel sums the stripes.

#define NSCALES 67
#define IMG_H 256
#define IMG_W 256
#define NPIX 65536
#define NLINES 2046          // 512 rows (H) + 512 cols (V) + 1022 diagonals (D)
#define LMAX_PAD 320         // 256 positions + 64 zero pad (max tap index 318)

// ws layout (doubles), all accumulators striped 8x by s = blockIdx & 7:
//  ACC(q,b,s) = 32 + s*64 + q*16 + b*8   q: 0=S1 1=S2 2=posCnt 3=sumAbsPrd
//  ROI(b,s)   = 544 + s*8 + b
//  T1(b,s)    = 640 + s*8 + b
// each (q,b,s) / (b,s) cell sits in its own region; hot lines never shared
// across components. memset covers doubles [0, 704).

#define ACC_OFF(q, b, s) (32 + (s) * 64 + (q) * 16 + (b) * 8)
#define ROI_OFF(b, s) (544 + (s) * 8 + (b))
#define T1_OFF(b, s) (640 + (s) * 8 + (b))

__device__ __forceinline__ double wave_red(double v) {
#pragma unroll
  for (int o = 32; o > 0; o >>= 1) v += __shfl_down(v, o, 64);
  return v;
}

__device__ __forceinline__ void decode_line(int id, int& b, int& base, int& stride, int& L) {
  if (id < 512) {                      // horizontal row
    b = id >> 8; int y = id & 255;
    base = y * IMG_W; stride = 1; L = IMG_W;
  } else if (id < 1024) {              // vertical column
    int t = id - 512; b = t >> 8;
    base = t & 255; stride = IMG_W; L = IMG_H;
  } else {                             // diagonal c = x - y in [-255,255]
    int t = id - 1024; b = (t >= 511) ? 1 : 0;
    int d = t - b * 511; int c = d - 255;
    int ac = (c < 0) ? -c : c;
    base = (c < 0) ? (-c) * IMG_W : c;
    stride = IMG_W + 1; L = 256 - ac;
  }
}

// #scales valid for quarter q (centers [64q, 64q+63]): s = 1+3k <= min(L-1-64q, 199)
__device__ __forceinline__ int scale_count(int L, int q) {
  int rem = L - 1 - (q << 6);
  int kcnt = (rem >= 1) ? ((rem - 1) / 3 + 1) : 0;
  return (kcnt > NSCALES) ? NSCALES : kcnt;
}

// Stage line; returns this tid's ROI value (position tid) for the ROI sum.
__device__ __forceinline__ float stage_line(
    const float* __restrict__ Pred, const float* __restrict__ GT,
    const float* __restrict__ ROI, int b, int base, int stride, int L,
    int tid, float4* bufA, float4* bufB) {
  const float* P = Pred + b * (3 * NPIX);
  const float* G = GT + b * (3 * NPIX);
  const float* R = ROI + b * NPIX;
  float r = 0.f, p0 = 0.f, p1 = 0.f, p2 = 0.f, g0 = 0.f, g1 = 0.f, g2 = 0.f;
  if (tid < L) {
    int a = base + tid * stride;
    r = R[a];
    p0 = P[a]; p1 = P[a + NPIX]; p2 = P[a + 2 * NPIX];
    g0 = G[a]; g1 = G[a + NPIX]; g2 = G[a + 2 * NPIX];
  }
  bufA[tid] = make_float4(r, p0, p1, p2);
  bufB[tid] = make_float4(g0, g1, g2, 0.f);
  if (tid < LMAX_PAD - 256) {
    bufA[256 + tid] = make_float4(0.f, 0.f, 0.f, 0.f);
    bufB[256 + tid] = make_float4(0.f, 0.f, 0.f, 0.f);
  }
  __syncthreads();
  return r;
}

extern "C" __global__ void __launch_bounds__(256, 8) pass1_kernel(
    const float* __restrict__ Pred, const float* __restrict__ GT,
    const float* __restrict__ ROI, double* __restrict__ ws) {
  __shared__ float4 bufA[LMAX_PAD];    // {r, p0, p1, p2}
  __shared__ float4 bufB[LMAX_PAD];    // {g0, g1, g2, 0}
  __shared__ double red[4][5];
  const int id = blockIdx.x;
  const int tid = threadIdx.x;
  const int wid = tid >> 6, lane = tid & 63;

  int b, base, stride, L;
  decode_line(id, b, base, stride, L);
  float stg_r = stage_line(Pred, GT, ROI, b, base, stride, L, tid, bufA, bufB);

  float f1 = 0.f, f2 = 0.f, fp = 0.f;
  int pci = 0;
  int P = 0;                            // task prefix
  for (int q = 0; q < 4; ++q) {
    const int Kq = scale_count(L, q);
    int k = (wid - P) & 3;              // round-robin task deal across 4 waves
    if (k < Kq) {
      const int c = (q << 6) + lane;
      const float4 cA = bufA[c];
      const float4 cB = bufB[c];
      const float cr = cA.x, cp0 = cA.y, cp1 = cA.z, cp2 = cA.w;
      const float cg0 = cB.x, cg1 = cB.y, cg2 = cB.z;
      const float4* tA = &bufA[c + 1 + 3 * k];
      const float4* tB = &bufB[c + 1 + 3 * k];
#pragma unroll 2
      for (; k < Kq; k += 4) {
        float4 t0 = tA[0];
        float4 t1 = tB[0];
        tA += 12; tB += 12;             // s += 12
        float rr = cr * t0.x;
#define L1BODY(cp, cg, tp, tg)                                   \
        {                                                        \
          float dP = rr * (cp - tp);                             \
          float dG = rr * (cg - tg);                             \
          float qq = dP * __builtin_amdgcn_rcpf(dG + 1e-5f);     \
          float aG = fabsf(dG);                                  \
          f1 += fmaxf(aG * qq, 0.f);                             \
          if (qq > 0.f) f2 += aG;                                \
          if (dG > 0.f) pci++;                                   \
          fp += fabsf(dP);                                       \
        }
        L1BODY(cp0, cg0, t0.y, t1.x)
        L1BODY(cp1, cg1, t0.z, t1.y)
        L1BODY(cp2, cg2, t0.w, t1.z)
#undef L1BODY
      }
    }
    P += Kq;
  }

  double w0 = wave_red((double)f1);
  double w1 = wave_red((double)f2);
  double w2 = wave_red((double)pci);
  double w3 = wave_red((double)fp);
  double w4 = wave_red((double)stg_r);  // ROI partial: position tid, once/block
  if (lane == 0) {
    red[wid][0] = w0; red[wid][1] = w1; red[wid][2] = w2;
    red[wid][3] = w3; red[wid][4] = w4;
  }
  __syncthreads();
  const int s = id & 7;                 // 8-way stripe, own line per cell
  if (tid < 4)
    unsafeAtomicAdd(&ws[ACC_OFF(tid, b, s)],
                    red[0][tid] + red[1][tid] + red[2][tid] + red[3][tid]);
  if (tid == 4 && id < 512)             // H rows tile the image exactly once
    unsafeAtomicAdd(&ws[ROI_OFF(b, s)],
                    red[0][4] + red[1][4] + red[2][4] + red[3][4]);
}

extern "C" __global__ void __launch_bounds__(256, 8) pass2_kernel(
    const float* __restrict__ Pred, const float* __restrict__ GT,
    const float* __restrict__ ROI, double* __restrict__ ws) {
  __shared__ float4 bufA[LMAX_PAD];
  __shared__ float4 bufB[LMAX_PAD];
  __shared__ double red[4];
  __shared__ float s_invC[2];
  const int id = blockIdx.x;
  const int tid = threadIdx.x;
  const int wid = tid >> 6, lane = tid & 63;

  int b, base, stride, L;
  decode_line(id, b, base, stride, L);
  if (tid < 2) {                        // invC per batch from striped pass1
    double S1 = 0.0, S2 = 0.0;          // sums (coherent across launch bound)
#pragma unroll
    for (int st = 0; st < 8; ++st) {
      S1 += ws[ACC_OFF(0, tid, st)];
      S2 += ws[ACC_OFF(1, tid, st)];
    }
    float cc = (float)(S1 / (S2 + 1e-4));
    s_invC[tid] = (cc > 1e-4f) ? (float)(1.0 / (double)cc) : 1.0f;
  }
  stage_line(Pred, GT, ROI, b, base, stride, L, tid, bufA, bufB);

  const float invC = s_invC[b];
  float f = 0.f;
  int P = 0;
  for (int q = 0; q < 4; ++q) {
    const int Kq = scale_count(L, q);
    int k = (wid - P) & 3;
    if (k < Kq) {
      const int c = (q << 6) + lane;
      const float4 cA = bufA[c];
      const float4 cB = bufB[c];
      const float cr = cA.x, cp0 = cA.y, cp1 = cA.z, cp2 = cA.w;
      const float cg0 = cB.x, cg1 = cB.y, cg2 = cB.z;
      const float4* tA = &bufA[c + 1 + 3 * k];
      const float4* tB = &bufB[c + 1 + 3 * k];
#pragma unroll 2
      for (; k < Kq; k += 4) {
        float4 t0 = tA[0];
        float4 t1 = tB[0];
        tA += 12; tB += 12;
        float rr = cr * t0.x;
        // |difGT - difPrd/c| = rr * |(g-gt) - (p-pt)*invC|   (rr in {0,1})
        f += rr * fabsf((cg0 - t1.x) - (cp0 - t0.y) * invC);
        f += rr * fabsf((cg1 - t1.y) - (cp1 - t0.z) * invC);
        f += rr * fabsf((cg2 - t1.z) - (cp2 - t0.w) * invC);
      }
    }
    P += Kq;
  }
  double t = wave_red((double)f);
  if (lane == 0) red[wid] = t;
  __syncthreads();
  if (tid == 0)
    unsafeAtomicAdd(&ws[T1_OFF(b, id & 7)],
                    red[0] + red[1] + red[2] + red[3]);
}

extern "C" __global__ void __launch_bounds__(64) final_kernel(
    const double* __restrict__ ws, float* __restrict__ out) {
  if (threadIdx.x == 0) {
    double loss = 0.0;
    for (int b = 0; b < 2; ++b) {
      double S1 = 0.0, S2 = 0.0, PC = 0.0, SP = 0.0, RS = 0.0, T1 = 0.0;
      for (int st = 0; st < 8; ++st) {
        S1 += ws[ACC_OFF(0, b, st)];
        S2 += ws[ACC_OFF(1, b, st)];
        PC += ws[ACC_OFF(2, b, st)];
        SP += ws[ACC_OFF(3, b, st)];
        RS += ws[ROI_OFF(b, st)];
        T1 += ws[T1_OFF(b, st)];
      }
      float cc = (float)(S1 / (S2 + 1e-4));
      out[1 + b] = cc;                  // NormConst
      double term1 = (cc > 1e-4f) ? T1 / (603.0 * 65536.0) : 0.0;
      float meanPrd = (float)(SP / PC);
      bool big = RS > 200.0;
      float t2 = (big && meanPrd > 30.f && cc > 10.f) ? (meanPrd - 30.f) : 0.f;
      float fact = 0.1f / (cc + 0.001f);
      float t3 = (big && meanPrd < 2.f && cc < 0.1f) ? (0.2f - meanPrd) * fact : 0.f;
      loss += term1 + (double)(t2 + t3);
    }
    out[0] = (float)loss;
  }
}

extern "C" void kernel_launch(void* const* d_in, const int* in_sizes, int n_in,
                              void* d_out, int out_size, void* d_ws, size_t ws_size,
                              hipStream_t stream) {
  (void)in_sizes; (void)n_in; (void)out_size; (void)ws_size;
  const float* Pred = (const float*)d_in[0];
  const float* GT = (const float*)d_in[1];
  const float* ROI = (const float*)d_in[2];
  float* out = (float*)d_out;
  double* ws = (double*)d_ws;

  hipMemsetAsync(d_ws, 0, 704 * sizeof(double), stream);  // striped accums
  hipLaunchKernelGGL(pass1_kernel, dim3(NLINES), dim3(256), 0, stream,
                     Pred, GT, ROI, ws);
  hipLaunchKernelGGL(pass2_kernel, dim3(NLINES), dim3(256), 0, stream,
                     Pred, GT, ROI, ws);
  hipLaunchKernelGGL(final_kernel, dim3(1), dim3(64), 0, stream, ws, out);
}